// Round 21
// baseline (10238.913 us; speedup 1.0000x reference)
//
#include <hip/hip_runtime.h>
#include <math.h>

#define HID   256
#define TLEN  512
#define NTHR  1024
#define GSIZE 8
#define NGRP  32
#define BBG   256            // batches per group

// h exchange: [NGRP][2 bufs][2 sel(hi,lo)][65536 u16]  (A-fragment order)
#define PLANE_U16 (16 * 8 * 512)                        // 65536 u16 = 128 KiB
#define HEX_U16   ((size_t)NGRP * 2 * 2 * PLANE_U16)    // 8M u16 = 16 MiB
#define FLAGS_OFF (HEX_U16 * 2)                         // bytes
#define NFLAGS    (NGRP * GSIZE)
#define CNT_OFF   (FLAGS_OFF + (size_t)NFLAGS * 4)
#define WS_NEEDED (CNT_OFF + 8 * 4)

typedef __attribute__((ext_vector_type(8))) short short8;
typedef __attribute__((ext_vector_type(4))) float f32x4;

typedef union {
    float4 f;
    uint4  u;
    short8 s;
} v16u;

static __device__ __forceinline__ unsigned short f2bf_rne(float x) {
    unsigned int u = __float_as_uint(x);
    unsigned int r = (u + 0x7FFFu + ((u >> 16) & 1u)) >> 16;
    return (unsigned short)r;
}
static __device__ __forceinline__ float sigf(float x) {
    return 1.0f / (1.0f + __expf(-x));
}
static __device__ __forceinline__ float tanhf_fast(float x) {
    return 1.0f - 2.0f / (1.0f + __expf(2.0f * x));
}

// ---- XCD-L2-coherent ops (sc0: bypass L1, complete at the XCD's L2) ----
// PROVEN RULE (r13, r19 failures): h data may use sc0 (L2) ONLY because the
// rendezvous flags use sc0 sc1 (MALL) — flag latency covers h visibility.
static __device__ __forceinline__ void issue_l2(const void* p, float4& a) {
    asm volatile("global_load_dwordx4 %0, %1, off sc0"
                 : "=&v"(a) : "v"(p) : "memory");
}
static __device__ __forceinline__ void store_short_l2(void* p, unsigned int v) {
    asm volatile("global_store_short %0, %1, off sc0"
                 :: "v"(p), "v"(v) : "memory");
}
// ---- device-coherent (MALL) ops for flags: sc0 sc1 — DO NOT weaken ----
static __device__ __forceinline__ unsigned int load_flag_dev(const unsigned int* p) {
    unsigned int v;
    asm volatile("global_load_dword %0, %1, off sc0 sc1\n\t"
                 "s_waitcnt vmcnt(0)"
                 : "=v"(v) : "v"(p) : "memory");
    return v;
}
static __device__ __forceinline__ void store_flag_dev(unsigned int* p, unsigned int v) {
    asm volatile("global_store_dword %0, %1, off sc0 sc1"
                 :: "v"(p), "v"(v) : "memory");
}

// flags + xcd counters init: device-coherent zeroing (replay-safe)
__global__ void init_flags(unsigned int* flags, unsigned int* cnt) {
    int i = blockIdx.x * 256 + threadIdx.x;
    if (i < NFLAGS) store_flag_dev(flags + i, 0u);
    if (i < 8) store_flag_dev(cnt + i, 0u);
}

// == coop weight-stationary, XCD-local groups, 8Mx2N wave grid (LDS-reuse) ==
__global__ __launch_bounds__(NTHR, 4) void lstm_coop14(
    const float* __restrict__ x,
    const float* __restrict__ W_ih,
    const float* __restrict__ W_hh,
    const float* __restrict__ b_ih,
    const float* __restrict__ b_hh,
    const float* __restrict__ W_fc,
    const float* __restrict__ b_fc,
    unsigned short* __restrict__ hexw,  // ws: split-bf16 h exchange planes
    unsigned int* __restrict__ flags,   // ws: [NGRP][GSIZE]
    unsigned int* __restrict__ xcnt,    // ws: [8] per-XCD slot counters
    float* __restrict__ out)
{
    const int tid  = threadIdx.x;
    const int wv   = tid >> 6;         // 0..15
    const int wm   = wv >> 1;          // 0..7 : owns M-tiles wm*2 + {0,1}
    const int wn   = wv & 1;           // half : owns units wn*16 + l15
    const int lane = tid & 63;
    const int l15  = lane & 15;
    const int l4   = lane >> 4;

    __shared__ unsigned short whi_s[64 * 512];   // 64 KiB  gate B-frags hi
    __shared__ unsigned short wlo_s[64 * 512];   // 64 KiB  gate B-frags lo
    __shared__ unsigned short fhi_s[8 * 512];    // 8 KiB   wfc B-frags hi (col 0)
    __shared__ unsigned short flo_s[8 * 512];    // 8 KiB   wfc B-frags lo
    __shared__ float wfc_s[HID];                 // for epilogue only
    __shared__ int slot_s;

    // ---- discover XCD, claim an XCD-local slot: group is truly XCD-local ----
    if (tid == 0) {
        unsigned int myxcd;
        asm volatile("s_getreg_b32 %0, hwreg(HW_REG_XCC_ID)" : "=s"(myxcd));
        myxcd &= 7u;
        unsigned int s = atomicAdd(&xcnt[myxcd], 1u) & 31u;   // 0..31 per XCD
        slot_s = (int)(myxcd * 32u + s);
    }
    __syncthreads();
    const int slot = slot_s;
    const int g    = slot >> 3;        // group 0..31 (4 per XCD, XCD-local)
    const int p    = slot & 7;         // producer index within group
    const int bbase = g * BBG;

    // ---- stage this block's 128 gate-rows into LDS (split bf16, B-frag order) ----
    #pragma unroll
    for (int i = 0; i < 4; ++i) {
        int tile = wv * 4 + i;            // 0..63 = nt*8 + kc
        int nt = tile >> 3, kc = tile & 7;
        int q = nt >> 1, half = nt & 1;
        int grow = q * 256 + p * 32 + half * 16 + l15;
        int k0 = kc * 32 + l4 * 8;
        const float* src = W_hh + (size_t)grow * HID + k0;
        float4 wa = *(const float4*)src;
        float4 wb = *(const float4*)(src + 4);
        float ff[8] = {wa.x, wa.y, wa.z, wa.w, wb.x, wb.y, wb.z, wb.w};
        short8 hi8, lo8;
        #pragma unroll
        for (int e = 0; e < 8; ++e) {
            unsigned int u = __float_as_uint(ff[e]);
            hi8[e] = (short)(u >> 16);
            float res = ff[e] - __uint_as_float(u & 0xffff0000u);
            lo8[e] = (short)f2bf_rne(res);
        }
        *(short8*)&whi_s[tile * 512 + lane * 8] = hi8;
        *(short8*)&wlo_s[tile * 512 + lane * 8] = lo8;
    }
    // ---- stage wfc B-frags: column n=0 holds W_fc, other columns zero ----
    if (wv < 8) {
        int kc = wv;
        short8 fh = {0,0,0,0,0,0,0,0};
        short8 fl = {0,0,0,0,0,0,0,0};
        if (l15 == 0) {
            #pragma unroll
            for (int e = 0; e < 8; ++e) {
                float wvv = W_fc[kc * 32 + l4 * 8 + e];
                unsigned int u = __float_as_uint(wvv);
                fh[e] = (short)(u >> 16);
                float res = wvv - __uint_as_float(u & 0xffff0000u);
                fl[e] = (short)f2bf_rne(res);
            }
        }
        *(short8*)&fhi_s[kc * 512 + lane * 8] = fh;
        *(short8*)&flo_s[kc * 512 + lane * 8] = fl;
    }
    if (tid < HID) wfc_s[tid] = W_fc[tid];

    // per-lane gate constants: q = gate (i,f,g,o); unit = p*32 + wn*16 + l15
    float biasv[4], wihv[4];
    #pragma unroll
    for (int q = 0; q < 4; ++q) {
        int grow = q * 256 + p * 32 + wn * 16 + l15;
        biasv[q] = b_ih[grow] + b_hh[grow];
        wihv[q]  = W_ih[grow];
    }
    const float bfc = b_fc[0];

    float c_r[2][4];
    #pragma unroll
    for (int mtl = 0; mtl < 2; ++mtl)
        #pragma unroll
        for (int r = 0; r < 4; ++r) c_r[mtl][r] = 0.0f;

    unsigned int* flg = flags + g * GSIZE;
    unsigned short* const gbase = hexw + (size_t)g * 4 * PLANE_U16;
    // plane(buf,sel) = gbase + (buf*2+sel)*PLANE_U16

    // h-store index constants: kw = wn*16 + l15
    const int stbase = 16 * (wn * 2 + (l15 >> 3)) * 8 + (l15 & 7);

    __syncthreads();

    // ================= step 0: gates = bias + x*wih (h=0) =================
    {
        unsigned short* hiw = gbase + (1 * 2 + 0) * PLANE_U16;  // h(1) -> buf 1
        unsigned short* low = gbase + (1 * 2 + 1) * PLANE_U16;
        #pragma unroll
        for (int mtl = 0; mtl < 2; ++mtl) {
            #pragma unroll
            for (int r = 0; r < 4; ++r) {
                float dv = x[bbase + (wm * 2 + mtl) * 16 + l4 * 4 + r];
                float gi = fmaf(dv, wihv[0], biasv[0]);
                float gf = fmaf(dv, wihv[1], biasv[1]);
                float gg = fmaf(dv, wihv[2], biasv[2]);
                float go = fmaf(dv, wihv[3], biasv[3]);
                float c = fmaf(sigf(gf), c_r[mtl][r], sigf(gi) * tanhf_fast(gg));
                c_r[mtl][r] = c;
                float h = sigf(go) * tanhf_fast(c);
                int idx = ((wm * 2 + mtl) * 8 + p) * 512 + (l4 * 4 + r) * 8 + stbase;
                unsigned int u = __float_as_uint(h);
                store_short_l2(hiw + idx, u >> 16);
                float res = h - __uint_as_float(u & 0xffff0000u);
                store_short_l2(low + idx, (unsigned int)f2bf_rne(res));
            }
        }
        asm volatile("s_waitcnt vmcnt(0)" ::: "memory");   // h at XCD L2
        __syncthreads();                                   // all waves drained
        if (tid == 0) store_flag_dev(&flg[p], 1u);
    }

    // ================= steps 1..511 =================
    #pragma unroll 1
    for (int t = 1; t < TLEN; ++t) {
        // wait for all 8 shares of h(t)  (flags via MALL)
        if (tid < GSIZE) {
            int guard = 0;
            while (load_flag_dev(&flg[tid]) < (unsigned int)t) {
                if (++guard > (1 << 18)) break;   // failsafe: never hang
            }
        }
        __syncthreads();

        const unsigned short* hir = gbase + ((t & 1) * 2 + 0) * PLANE_U16 + lane * 8;
        const unsigned short* lor = gbase + ((t & 1) * 2 + 1) * PLANE_U16 + lane * 8;

        f32x4 acc[2][4];
        #pragma unroll
        for (int mtl = 0; mtl < 2; ++mtl)
            #pragma unroll
            for (int q = 0; q < 4; ++q)
                #pragma unroll
                for (int r = 0; r < 4; ++r) acc[mtl][q][r] = 0.0f;
        f32x4 accd[2];
        #pragma unroll
        for (int mtl = 0; mtl < 2; ++mtl)
            #pragma unroll
            for (int r = 0; r < 4; ++r) accd[mtl][r] = 0.0f;

        // 3-deep rotation, 4 loads per kc (2 mt x hi/lo)
        v16u pfh[3][2], pfl[3][2];
        #pragma unroll
        for (int k0 = 0; k0 < 2; ++k0) {
            #pragma unroll
            for (int mtl = 0; mtl < 2; ++mtl) {
                int off = ((wm * 2 + mtl) * 8 + k0) * 512;
                issue_l2(hir + off, pfh[k0][mtl].f);
                issue_l2(lor + off, pfl[k0][mtl].f);
            }
        }

        #pragma unroll
        for (int kc = 0; kc < 8; ++kc) {
            if (kc < 6) {
                #pragma unroll
                for (int mtl = 0; mtl < 2; ++mtl) {
                    int off = ((wm * 2 + mtl) * 8 + (kc + 2)) * 512;
                    issue_l2(hir + off, pfh[(kc + 2) % 3][mtl].f);
                    issue_l2(lor + off, pfl[(kc + 2) % 3][mtl].f);
                }
                asm volatile("s_waitcnt vmcnt(8)" ::: "memory");
            } else if (kc == 6) {
                asm volatile("s_waitcnt vmcnt(4)" ::: "memory");
            } else {
                asm volatile("s_waitcnt vmcnt(0)" ::: "memory");
            }
            __builtin_amdgcn_sched_barrier(0);

            const v16u ha0 = pfh[kc % 3][0];
            const v16u la0 = pfl[kc % 3][0];
            const v16u ha1 = pfh[kc % 3][1];
            const v16u la1 = pfl[kc % 3][1];

            #pragma unroll
            for (int q = 0; q < 4; ++q) {
                int tile = (q * 2 + wn) * 8 + kc;
                short8 bhi = *(const short8*)&whi_s[tile * 512 + lane * 8];
                short8 blo = *(const short8*)&wlo_s[tile * 512 + lane * 8];
                acc[0][q] = __builtin_amdgcn_mfma_f32_16x16x32_bf16(ha0.s, bhi, acc[0][q], 0, 0, 0);
                acc[0][q] = __builtin_amdgcn_mfma_f32_16x16x32_bf16(la0.s, bhi, acc[0][q], 0, 0, 0);
                acc[0][q] = __builtin_amdgcn_mfma_f32_16x16x32_bf16(ha0.s, blo, acc[0][q], 0, 0, 0);
                acc[1][q] = __builtin_amdgcn_mfma_f32_16x16x32_bf16(ha1.s, bhi, acc[1][q], 0, 0, 0);
                acc[1][q] = __builtin_amdgcn_mfma_f32_16x16x32_bf16(la1.s, bhi, acc[1][q], 0, 0, 0);
                acc[1][q] = __builtin_amdgcn_mfma_f32_16x16x32_bf16(ha1.s, blo, acc[1][q], 0, 0, 0);
            }
            // d-column MFMAs: B holds wfc in col 0 (computed by both wn halves)
            {
                short8 fh = *(const short8*)&fhi_s[kc * 512 + lane * 8];
                short8 fl = *(const short8*)&flo_s[kc * 512 + lane * 8];
                accd[0] = __builtin_amdgcn_mfma_f32_16x16x32_bf16(ha0.s, fh, accd[0], 0, 0, 0);
                accd[0] = __builtin_amdgcn_mfma_f32_16x16x32_bf16(la0.s, fh, accd[0], 0, 0, 0);
                accd[0] = __builtin_amdgcn_mfma_f32_16x16x32_bf16(ha0.s, fl, accd[0], 0, 0, 0);
                accd[1] = __builtin_amdgcn_mfma_f32_16x16x32_bf16(ha1.s, fh, accd[1], 0, 0, 0);
                accd[1] = __builtin_amdgcn_mfma_f32_16x16x32_bf16(la1.s, fh, accd[1], 0, 0, 0);
                accd[1] = __builtin_amdgcn_mfma_f32_16x16x32_bf16(ha1.s, fl, accd[1], 0, 0, 0);
            }
        }

        // d(t-1): lanes with l15==0 hold col 0 = d for batch (wm*2+mtl)*16+l4*4+r
        if (p == 0 && wn == 0 && l15 == 0) {
            #pragma unroll
            for (int mtl = 0; mtl < 2; ++mtl)
                #pragma unroll
                for (int r = 0; r < 4; ++r)
                    out[(size_t)(bbase + (wm * 2 + mtl) * 16 + l4 * 4 + r) * TLEN + (t - 1)]
                        = accd[mtl][r] + bfc;
        }
        float dreg[2][4];
        #pragma unroll
        for (int mtl = 0; mtl < 2; ++mtl)
            #pragma unroll
            for (int r = 0; r < 4; ++r)
                dreg[mtl][r] = __shfl(accd[mtl][r], lane & 48) + bfc;

        // cell update + h(t+1) split store (XCD-L2 coherent)
        unsigned short* hiw = gbase + ((((t + 1) & 1)) * 2 + 0) * PLANE_U16;
        unsigned short* low = gbase + ((((t + 1) & 1)) * 2 + 1) * PLANE_U16;
        #pragma unroll
        for (int mtl = 0; mtl < 2; ++mtl) {
            #pragma unroll
            for (int r = 0; r < 4; ++r) {
                float dv = dreg[mtl][r];
                float gi = acc[mtl][0][r] + fmaf(dv, wihv[0], biasv[0]);
                float gf = acc[mtl][1][r] + fmaf(dv, wihv[1], biasv[1]);
                float gg = acc[mtl][2][r] + fmaf(dv, wihv[2], biasv[2]);
                float go = acc[mtl][3][r] + fmaf(dv, wihv[3], biasv[3]);
                float c = fmaf(sigf(gf), c_r[mtl][r], sigf(gi) * tanhf_fast(gg));
                c_r[mtl][r] = c;
                float h = sigf(go) * tanhf_fast(c);
                int idx = ((wm * 2 + mtl) * 8 + p) * 512 + (l4 * 4 + r) * 8 + stbase;
                unsigned int u = __float_as_uint(h);
                store_short_l2(hiw + idx, u >> 16);
                float res = h - __uint_as_float(u & 0xffff0000u);
                store_short_l2(low + idx, (unsigned int)f2bf_rne(res));
            }
        }
        asm volatile("s_waitcnt vmcnt(0)" ::: "memory");   // h at XCD L2
        __syncthreads();                                   // all waves drained
        if (tid == 0) store_flag_dev(&flg[p], (unsigned int)(t + 1));
    }

    // ================= epilogue: out[:,511] = h(512)·wfc + bfc =================
    {
        if (tid < GSIZE) {
            int guard = 0;
            while (load_flag_dev(&flg[tid]) < (unsigned int)TLEN) {
                if (++guard > (1 << 18)) break;
            }
        }
        __syncthreads();
        if (p == 0) {
            const int mt = wv;   // epilogue mapping independent of main loop
            const unsigned short* hir = gbase + (0 * 2 + 0) * PLANE_U16
                                      + (mt * 8) * 512 + lane * 8;
            const unsigned short* lor = gbase + (0 * 2 + 1) * PLANE_U16
                                      + (mt * 8) * 512 + lane * 8;
            float dsum = 0.0f;
            #pragma unroll
            for (int kc = 0; kc < 8; ++kc) {
                v16u va, vb;
                issue_l2(hir + kc * 512, va.f);
                issue_l2(lor + kc * 512, vb.f);
                asm volatile("s_waitcnt vmcnt(0)" ::: "memory");
                __builtin_amdgcn_sched_barrier(0);
                const float* wf = &wfc_s[kc * 32 + l4 * 8];
                unsigned int uu[4] = {va.u.x, va.u.y, va.u.z, va.u.w};
                unsigned int ll[4] = {vb.u.x, vb.u.y, vb.u.z, vb.u.w};
                #pragma unroll
                for (int i = 0; i < 4; ++i) {
                    float h0 = __uint_as_float(uu[i] << 16)
                             + __uint_as_float(ll[i] << 16);
                    float h1 = __uint_as_float(uu[i] & 0xffff0000u)
                             + __uint_as_float(ll[i] & 0xffff0000u);
                    dsum = fmaf(h0, wf[2 * i + 0], dsum);
                    dsum = fmaf(h1, wf[2 * i + 1], dsum);
                }
            }
            dsum += __shfl_xor(dsum, 16);
            dsum += __shfl_xor(dsum, 32);
            if (lane < 16)
                out[(size_t)(bbase + mt * 16 + lane) * TLEN + (TLEN - 1)] = dsum + bfc;
        }
    }
}

// ================= fallback (r8 kernel, needs no workspace) =================
#define BB 32
__global__ __launch_bounds__(NTHR, 4) void lstm_mfma7(
    const float* __restrict__ x, const float* __restrict__ W_ih,
    const float* __restrict__ W_hh, const float* __restrict__ b_ih,
    const float* __restrict__ b_hh, const float* __restrict__ W_fc,
    const float* __restrict__ b_fc, float* __restrict__ out)
{
    const int tid = threadIdx.x;
    const int wave = tid >> 6;
    const int lane = tid & 63;
    const int l15 = lane & 15;
    const int l4 = lane >> 4;
    const int bbase = blockIdx.x * BB;

    __shared__ unsigned short hhi[2][16 * 512];
    __shared__ unsigned short hlo[2][16 * 512];
    __shared__ float dpart[16][BB];
    __shared__ float inp_s[BB];

    for (int i = tid; i < 16 * 512; i += NTHR) { hhi[0][i] = 0; hlo[0][i] = 0; }
    if (tid < BB) inp_s[tid] = x[bbase + tid];

    float biasv[4], wihv[4];
    #pragma unroll
    for (int q = 0; q < 4; ++q) {
        int gg = 256 * q + 16 * wave + l15;
        biasv[q] = b_ih[gg] + b_hh[gg];
        wihv[q] = W_ih[gg];
    }
    const float wfc = W_fc[16 * wave + l15];
    const float bfc = b_fc[0];
    const float* __restrict__ wrow = W_hh + (size_t)(16 * wave + l15) * HID + l4 * 8;
    const int kc_w = wave >> 1;
    const int kwhi = (wave & 1) * 2 + (l15 >> 3);
    const int elemw = l15 & 7;

    float c_r[2][4];
    #pragma unroll
    for (int m = 0; m < 2; ++m)
        #pragma unroll
        for (int r = 0; r < 4; ++r) c_r[m][r] = 0.0f;
    __syncthreads();

    #pragma unroll 1
    for (int t = 0; t < TLEN; ++t) {
        const int p = t & 1;
        f32x4 acc[2][4];
        {
            float dv[2][4];
            #pragma unroll
            for (int m = 0; m < 2; ++m)
                #pragma unroll
                for (int r = 0; r < 4; ++r) dv[m][r] = inp_s[16 * m + 4 * l4 + r];
            #pragma unroll
            for (int m = 0; m < 2; ++m)
                #pragma unroll
                for (int q = 0; q < 4; ++q)
                    #pragma unroll
                    for (int r = 0; r < 4; ++r)
                        acc[m][q][r] = fmaf(dv[m][r], wihv[q], biasv[q]);
        }
        #pragma unroll
        for (int kc = 0; kc < 8; ++kc) {
            short8 ahi[2], alo[2];
            #pragma unroll
            for (int m = 0; m < 2; ++m) {
                int aoff = (m * 8 + kc) * 512 + lane * 8;
                ahi[m] = *(const short8*)&hhi[p][aoff];
                alo[m] = *(const short8*)&hlo[p][aoff];
            }
            #pragma unroll
            for (int q = 0; q < 4; ++q) {
                const float* src = wrow + (size_t)q * 256 * HID + kc * 32;
                float4 wa = *(const float4*)src;
                float4 wb = *(const float4*)(src + 4);
                float ff[8] = {wa.x, wa.y, wa.z, wa.w, wb.x, wb.y, wb.z, wb.w};
                short8 bhi, blo;
                #pragma unroll
                for (int e = 0; e < 8; ++e) {
                    unsigned int u = __float_as_uint(ff[e]);
                    bhi[e] = (short)(u >> 16);
                    float res = ff[e] - __uint_as_float(u & 0xffff0000u);
                    blo[e] = (short)(__float_as_uint(res) >> 16);
                }
                #pragma unroll
                for (int m = 0; m < 2; ++m) {
                    acc[m][q] = __builtin_amdgcn_mfma_f32_16x16x32_bf16(ahi[m], bhi, acc[m][q], 0, 0, 0);
                    acc[m][q] = __builtin_amdgcn_mfma_f32_16x16x32_bf16(alo[m], bhi, acc[m][q], 0, 0, 0);
                    acc[m][q] = __builtin_amdgcn_mfma_f32_16x16x32_bf16(ahi[m], blo, acc[m][q], 0, 0, 0);
                }
            }
        }
        #pragma unroll
        for (int m = 0; m < 2; ++m) {
            #pragma unroll
            for (int r = 0; r < 4; ++r) {
                float gi = acc[m][0][r];
                float gf = acc[m][1][r];
                float gg = acc[m][2][r];
                float go = acc[m][3][r];
                float c = fmaf(sigf(gf), c_r[m][r], sigf(gi) * tanhf_fast(gg));
                c_r[m][r] = c;
                float h = sigf(go) * tanhf_fast(c);
                unsigned short hh = f2bf_rne(h);
                float hres = h - __uint_as_float(__float_as_uint(h) & 0xffff0000u);
                int haddr = (m * 8 + kc_w) * 512 + ((4 * l4 + r) + 16 * kwhi) * 8 + elemw;
                hhi[p ^ 1][haddr] = hh;
                hlo[p ^ 1][haddr] = f2bf_rne(hres);
                float s = h * wfc;
                s += __shfl_xor(s, 1);
                s += __shfl_xor(s, 2);
                s += __shfl_xor(s, 4);
                s += __shfl_xor(s, 8);
                if (l15 == 0) dpart[wave][16 * m + 4 * l4 + r] = s;
            }
        }
        __syncthreads();
        if (tid < BB) {
            float s = bfc;
            #pragma unroll
            for (int w = 0; w < 16; ++w) s += dpart[w][tid];
            inp_s[tid] = s;
            out[(size_t)(bbase + tid) * TLEN + t] = s;
        }
        __syncthreads();
    }
}

extern "C" void kernel_launch(void* const* d_in, const int* in_sizes, int n_in,
                              void* d_out, int out_size, void* d_ws, size_t ws_size,
                              hipStream_t stream) {
    const float* x    = (const float*)d_in[0];
    const float* W_ih = (const float*)d_in[1];
    const float* W_hh = (const float*)d_in[2];
    const float* b_ih = (const float*)d_in[3];
    const float* b_hh = (const float*)d_in[4];
    const float* W_fc = (const float*)d_in[5];
    const float* b_fc = (const float*)d_in[6];
    float* out = (float*)d_out;

    const int BATCH = in_sizes[0];   // 8192

    if (ws_size >= WS_NEEDED) {
        unsigned int* flags = (unsigned int*)((char*)d_ws + FLAGS_OFF);
        unsigned int* xcnt  = (unsigned int*)((char*)d_ws + CNT_OFF);
        init_flags<<<1, 256, 0, stream>>>(flags, xcnt);
        lstm_coop14<<<BATCH / BBG * GSIZE, NTHR, 0, stream>>>(
            x, W_ih, W_hh, b_ih, b_hh, W_fc, b_fc,
            (unsigned short*)d_ws, flags, xcnt, out);
    } else {
        lstm_mfma7<<<BATCH / BB, NTHR, 0, stream>>>(
            x, W_ih, W_hh, b_ih, b_hh, W_fc, b_fc, out);
    }
}

// Round 22
// 7012.955 us; speedup vs baseline: 1.4600x; 1.4600x over previous
//
#include <hip/hip_runtime.h>
#include <math.h>

#define HID   256
#define TLEN  512
#define NTHR  1024
#define GSIZE 8
#define NGRP  32
#define BBG   256            // batches per group

// h exchange: [NGRP][2 bufs][2 sel(hi,lo)][65536 u16]  (A-fragment order)
#define PLANE_U16 (16 * 8 * 512)                        // 65536 u16 = 128 KiB
#define HEX_U16   ((size_t)NGRP * 2 * 2 * PLANE_U16)    // 8M u16 = 16 MiB
#define FLAGS_OFF (HEX_U16 * 2)                         // bytes
#define NFLAGS    (NGRP * GSIZE)
#define CNT_OFF   (FLAGS_OFF + (size_t)NFLAGS * 4)
#define WS_NEEDED (CNT_OFF + 8 * 4)

typedef __attribute__((ext_vector_type(8))) short short8;
typedef __attribute__((ext_vector_type(4))) float f32x4;

typedef union {
    float4 f;
    uint4  u;
    short8 s;
} v16u;

static __device__ __forceinline__ unsigned short f2bf_rne(float x) {
    unsigned int u = __float_as_uint(x);
    unsigned int r = (u + 0x7FFFu + ((u >> 16) & 1u)) >> 16;
    return (unsigned short)r;
}
static __device__ __forceinline__ float sigf(float x) {
    return 1.0f / (1.0f + __expf(-x));
}
static __device__ __forceinline__ float tanhf_fast(float x) {
    return 1.0f - 2.0f / (1.0f + __expf(2.0f * x));
}

// ---- XCD-L2-coherent ops (sc0: bypass L1, complete at the XCD's L2) ----
// PROVEN RULE (r13, r19 failures): h data may use sc0 (L2) ONLY because the
// rendezvous flags use sc0 sc1 (MALL) — flag latency covers h visibility.
static __device__ __forceinline__ void issue_l2(const void* p, float4& a) {
    asm volatile("global_load_dwordx4 %0, %1, off sc0"
                 : "=&v"(a) : "v"(p) : "memory");
}
static __device__ __forceinline__ void store_short_l2(void* p, unsigned int v) {
    asm volatile("global_store_short %0, %1, off sc0"
                 :: "v"(p), "v"(v) : "memory");
}
// ---- device-coherent (MALL) ops for flags: sc0 sc1 — DO NOT weaken ----
static __device__ __forceinline__ unsigned int load_flag_dev(const unsigned int* p) {
    unsigned int v;
    asm volatile("global_load_dword %0, %1, off sc0 sc1\n\t"
                 "s_waitcnt vmcnt(0)"
                 : "=v"(v) : "v"(p) : "memory");
    return v;
}
static __device__ __forceinline__ void store_flag_dev(unsigned int* p, unsigned int v) {
    asm volatile("global_store_dword %0, %1, off sc0 sc1"
                 :: "v"(p), "v"(v) : "memory");
}

// flags + xcd counters init: device-coherent zeroing (replay-safe)
__global__ void init_flags(unsigned int* flags, unsigned int* cnt) {
    int i = blockIdx.x * 256 + threadIdx.x;
    if (i < NFLAGS) store_flag_dev(flags + i, 0u);
    if (i < 8) store_flag_dev(cnt + i, 0u);
}

// ==== cooperative weight-stationary kernel, XCD-local groups via XCC_ID ====
__global__ __launch_bounds__(NTHR, 4) void lstm_coop11(
    const float* __restrict__ x,
    const float* __restrict__ W_ih,
    const float* __restrict__ W_hh,
    const float* __restrict__ b_ih,
    const float* __restrict__ b_hh,
    const float* __restrict__ W_fc,
    const float* __restrict__ b_fc,
    unsigned short* __restrict__ hexw,  // ws: split-bf16 h exchange planes
    unsigned int* __restrict__ flags,   // ws: [NGRP][GSIZE]
    unsigned int* __restrict__ xcnt,    // ws: [8] per-XCD slot counters
    float* __restrict__ out)
{
    const int tid  = threadIdx.x;
    const int mt   = tid >> 6;         // wave = M-tile (16 batches)
    const int lane = tid & 63;
    const int l15  = lane & 15;
    const int l4   = lane >> 4;

    __shared__ unsigned short whi_s[64 * 512];   // 64 KiB  gate B-frags hi
    __shared__ unsigned short wlo_s[64 * 512];   // 64 KiB  gate B-frags lo
    __shared__ unsigned short fhi_s[8 * 512];    // 8 KiB   wfc B-frags hi (col 0)
    __shared__ unsigned short flo_s[8 * 512];    // 8 KiB   wfc B-frags lo
    __shared__ float wfc_s[HID];                 // for epilogue only
    __shared__ int slot_s;

    // ---- discover XCD, claim an XCD-local slot: group is truly XCD-local ----
    if (tid == 0) {
        unsigned int myxcd;
        asm volatile("s_getreg_b32 %0, hwreg(HW_REG_XCC_ID)" : "=s"(myxcd));
        myxcd &= 7u;
        unsigned int s = atomicAdd(&xcnt[myxcd], 1u) & 31u;   // 0..31 per XCD
        slot_s = (int)(myxcd * 32u + s);
    }
    __syncthreads();
    const int slot = slot_s;
    const int g    = slot >> 3;        // group 0..31 (4 per XCD, XCD-local)
    const int p    = slot & 7;         // producer index within group
    const int bbase = g * BBG;

    // ---- stage this block's 128 gate-rows into LDS (split bf16, B-frag order) ----
    #pragma unroll
    for (int i = 0; i < 4; ++i) {
        int tile = mt * 4 + i;            // 0..63 = nt*8 + kc
        int nt = tile >> 3, kc = tile & 7;
        int q = nt >> 1, half = nt & 1;
        int grow = q * 256 + p * 32 + half * 16 + l15;
        int k0 = kc * 32 + l4 * 8;
        const float* src = W_hh + (size_t)grow * HID + k0;
        float4 wa = *(const float4*)src;
        float4 wb = *(const float4*)(src + 4);
        float ff[8] = {wa.x, wa.y, wa.z, wa.w, wb.x, wb.y, wb.z, wb.w};
        short8 hi8, lo8;
        #pragma unroll
        for (int e = 0; e < 8; ++e) {
            unsigned int u = __float_as_uint(ff[e]);
            hi8[e] = (short)(u >> 16);
            float res = ff[e] - __uint_as_float(u & 0xffff0000u);
            lo8[e] = (short)f2bf_rne(res);
        }
        *(short8*)&whi_s[tile * 512 + lane * 8] = hi8;
        *(short8*)&wlo_s[tile * 512 + lane * 8] = lo8;
    }
    // ---- stage wfc B-frags: column n=0 holds W_fc, other columns zero ----
    if (mt < 8) {
        int kc = mt;
        short8 fh = {0,0,0,0,0,0,0,0};
        short8 fl = {0,0,0,0,0,0,0,0};
        if (l15 == 0) {
            #pragma unroll
            for (int e = 0; e < 8; ++e) {
                float wv = W_fc[kc * 32 + l4 * 8 + e];
                unsigned int u = __float_as_uint(wv);
                fh[e] = (short)(u >> 16);
                float res = wv - __uint_as_float(u & 0xffff0000u);
                fl[e] = (short)f2bf_rne(res);
            }
        }
        *(short8*)&fhi_s[kc * 512 + lane * 8] = fh;
        *(short8*)&flo_s[kc * 512 + lane * 8] = fl;
    }
    if (tid < HID) wfc_s[tid] = W_fc[tid];

    // per-lane gate constants: nt = q*2+half -> grow
    float biasv[8], wihv[8];
    #pragma unroll
    for (int nt = 0; nt < 8; ++nt) {
        int grow = (nt >> 1) * 256 + p * 32 + (nt & 1) * 16 + l15;
        biasv[nt] = b_ih[grow] + b_hh[grow];
        wihv[nt]  = W_ih[grow];
    }
    const float bfc = b_fc[0];

    float c_r[2][4];
    #pragma unroll
    for (int half = 0; half < 2; ++half)
        #pragma unroll
        for (int r = 0; r < 4; ++r) c_r[half][r] = 0.0f;

    unsigned int* flg = flags + g * GSIZE;
    unsigned short* const gbase = hexw + (size_t)g * 4 * PLANE_U16;
    // plane(buf,sel) = gbase + (buf*2+sel)*PLANE_U16

    __syncthreads();

    // ================= step 0: gates = bias + x*wih (h=0) =================
    {
        float dreg[4];
        #pragma unroll
        for (int r = 0; r < 4; ++r) dreg[r] = x[bbase + mt * 16 + l4 * 4 + r];

        unsigned short* hiw = gbase + (1 * 2 + 0) * PLANE_U16;  // h(1) -> buf 1
        unsigned short* low = gbase + (1 * 2 + 1) * PLANE_U16;
        #pragma unroll
        for (int half = 0; half < 2; ++half) {
            #pragma unroll
            for (int r = 0; r < 4; ++r) {
                float gi = fmaf(dreg[r], wihv[0 + half], biasv[0 + half]);
                float gf = fmaf(dreg[r], wihv[2 + half], biasv[2 + half]);
                float gg = fmaf(dreg[r], wihv[4 + half], biasv[4 + half]);
                float go = fmaf(dreg[r], wihv[6 + half], biasv[6 + half]);
                float c = fmaf(sigf(gf), c_r[half][r], sigf(gi) * tanhf_fast(gg));
                c_r[half][r] = c;
                float h = sigf(go) * tanhf_fast(c);
                int lane_d = l4 * 4 + r + 16 * (half * 2 + (l15 >> 3));
                int idx = (mt * 8 + p) * 512 + lane_d * 8 + (l15 & 7);
                unsigned int u = __float_as_uint(h);
                store_short_l2(hiw + idx, u >> 16);
                float res = h - __uint_as_float(u & 0xffff0000u);
                store_short_l2(low + idx, (unsigned int)f2bf_rne(res));
            }
        }
        asm volatile("s_waitcnt vmcnt(0)" ::: "memory");   // h at XCD L2
        __syncthreads();                                   // all waves drained
        if (tid == 0) store_flag_dev(&flg[p], 1u);
    }

    // ================= steps 1..511 =================
    #pragma unroll 1
    for (int t = 1; t < TLEN; ++t) {
        // wait for all 8 shares of h(t)  (flags via MALL)
        if (tid < GSIZE) {
            int guard = 0;
            while (load_flag_dev(&flg[tid]) < (unsigned int)t) {
                if (++guard > (1 << 18)) break;   // failsafe: never hang
            }
        }
        __syncthreads();

        const unsigned short* hir = gbase + ((t & 1) * 2 + 0) * PLANE_U16
                                  + (mt * 8) * 512 + lane * 8;
        const unsigned short* lor = gbase + ((t & 1) * 2 + 1) * PLANE_U16
                                  + (mt * 8) * 512 + lane * 8;

        f32x4 acc[8];
        #pragma unroll
        for (int nt = 0; nt < 8; ++nt)
            #pragma unroll
            for (int r = 0; r < 4; ++r) acc[nt][r] = 0.0f;
        f32x4 accd = {0.0f, 0.0f, 0.0f, 0.0f};   // d-column accumulator

        v16u pfh[3], pfl[3];
        issue_l2(hir, pfh[0].f);
        issue_l2(lor, pfl[0].f);
        issue_l2(hir + 512, pfh[1].f);
        issue_l2(lor + 512, pfl[1].f);

        #pragma unroll
        for (int kc = 0; kc < 8; ++kc) {
            if (kc < 6) {
                issue_l2(hir + (kc + 2) * 512, pfh[(kc + 2) % 3].f);
                issue_l2(lor + (kc + 2) * 512, pfl[(kc + 2) % 3].f);
                asm volatile("s_waitcnt vmcnt(4)" ::: "memory");
            } else if (kc == 6) {
                asm volatile("s_waitcnt vmcnt(2)" ::: "memory");
            } else {
                asm volatile("s_waitcnt vmcnt(0)" ::: "memory");
            }
            __builtin_amdgcn_sched_barrier(0);

            const v16u ha = pfh[kc % 3];
            const v16u la = pfl[kc % 3];

            #pragma unroll
            for (int nt = 0; nt < 8; ++nt) {
                short8 bhi = *(const short8*)&whi_s[(nt * 8 + kc) * 512 + lane * 8];
                short8 blo = *(const short8*)&wlo_s[(nt * 8 + kc) * 512 + lane * 8];
                acc[nt] = __builtin_amdgcn_mfma_f32_16x16x32_bf16(ha.s, bhi, acc[nt], 0, 0, 0);
                acc[nt] = __builtin_amdgcn_mfma_f32_16x16x32_bf16(la.s, bhi, acc[nt], 0, 0, 0);
                acc[nt] = __builtin_amdgcn_mfma_f32_16x16x32_bf16(ha.s, blo, acc[nt], 0, 0, 0);
            }
            // d-column MFMAs: B holds wfc in col 0
            {
                short8 fh = *(const short8*)&fhi_s[kc * 512 + lane * 8];
                short8 fl = *(const short8*)&flo_s[kc * 512 + lane * 8];
                accd = __builtin_amdgcn_mfma_f32_16x16x32_bf16(ha.s, fh, accd, 0, 0, 0);
                accd = __builtin_amdgcn_mfma_f32_16x16x32_bf16(la.s, fh, accd, 0, 0, 0);
                accd = __builtin_amdgcn_mfma_f32_16x16x32_bf16(ha.s, fl, accd, 0, 0, 0);
            }
        }

        // d(t-1): lanes with l15==0 hold col 0 = d for batch mt*16 + l4*4 + r
        if (p == 0 && l15 == 0) {
            #pragma unroll
            for (int r = 0; r < 4; ++r)
                out[(size_t)(bbase + mt * 16 + l4 * 4 + r) * TLEN + (t - 1)] = accd[r] + bfc;
        }
        float dreg[4];
        #pragma unroll
        for (int r = 0; r < 4; ++r)
            dreg[r] = __shfl(accd[r], lane & 48) + bfc;   // broadcast from l15==0 lane

        // cell update + h(t+1) split store (XCD-L2 coherent)
        unsigned short* hiw = gbase + ((((t + 1) & 1)) * 2 + 0) * PLANE_U16;
        unsigned short* low = gbase + ((((t + 1) & 1)) * 2 + 1) * PLANE_U16;
        #pragma unroll
        for (int half = 0; half < 2; ++half) {
            #pragma unroll
            for (int r = 0; r < 4; ++r) {
                float gi = acc[0 + half][r] + fmaf(dreg[r], wihv[0 + half], biasv[0 + half]);
                float gf = acc[2 + half][r] + fmaf(dreg[r], wihv[2 + half], biasv[2 + half]);
                float gg = acc[4 + half][r] + fmaf(dreg[r], wihv[4 + half], biasv[4 + half]);
                float go = acc[6 + half][r] + fmaf(dreg[r], wihv[6 + half], biasv[6 + half]);
                float c = fmaf(sigf(gf), c_r[half][r], sigf(gi) * tanhf_fast(gg));
                c_r[half][r] = c;
                float h = sigf(go) * tanhf_fast(c);
                int lane_d = l4 * 4 + r + 16 * (half * 2 + (l15 >> 3));
                int idx = (mt * 8 + p) * 512 + lane_d * 8 + (l15 & 7);
                unsigned int u = __float_as_uint(h);
                store_short_l2(hiw + idx, u >> 16);
                float res = h - __uint_as_float(u & 0xffff0000u);
                store_short_l2(low + idx, (unsigned int)f2bf_rne(res));
            }
        }
        asm volatile("s_waitcnt vmcnt(0)" ::: "memory");   // h at XCD L2
        __syncthreads();                                   // all waves drained
        if (tid == 0) store_flag_dev(&flg[p], (unsigned int)(t + 1));
    }

    // ================= epilogue: out[:,511] = h(512)·wfc + bfc =================
    {
        if (tid < GSIZE) {
            int guard = 0;
            while (load_flag_dev(&flg[tid]) < (unsigned int)TLEN) {
                if (++guard > (1 << 18)) break;
            }
        }
        __syncthreads();
        if (p == 0) {
            const unsigned short* hir = gbase + (0 * 2 + 0) * PLANE_U16
                                      + (mt * 8) * 512 + lane * 8;
            const unsigned short* lor = gbase + (0 * 2 + 1) * PLANE_U16
                                      + (mt * 8) * 512 + lane * 8;
            float dsum = 0.0f;
            #pragma unroll
            for (int kc = 0; kc < 8; ++kc) {
                v16u va, vb;
                issue_l2(hir + kc * 512, va.f);
                issue_l2(lor + kc * 512, vb.f);
                asm volatile("s_waitcnt vmcnt(0)" ::: "memory");
                __builtin_amdgcn_sched_barrier(0);
                const float* wf = &wfc_s[kc * 32 + l4 * 8];
                unsigned int uu[4] = {va.u.x, va.u.y, va.u.z, va.u.w};
                unsigned int ll[4] = {vb.u.x, vb.u.y, vb.u.z, vb.u.w};
                #pragma unroll
                for (int i = 0; i < 4; ++i) {
                    float h0 = __uint_as_float(uu[i] << 16)
                             + __uint_as_float(ll[i] << 16);
                    float h1 = __uint_as_float(uu[i] & 0xffff0000u)
                             + __uint_as_float(ll[i] & 0xffff0000u);
                    dsum = fmaf(h0, wf[2 * i + 0], dsum);
                    dsum = fmaf(h1, wf[2 * i + 1], dsum);
                }
            }
            dsum += __shfl_xor(dsum, 16);
            dsum += __shfl_xor(dsum, 32);
            if (lane < 16)
                out[(size_t)(bbase + mt * 16 + lane) * TLEN + (TLEN - 1)] = dsum + bfc;
        }
    }
}

// ================= fallback (r8 kernel, needs no workspace) =================
#define BB 32
__global__ __launch_bounds__(NTHR, 4) void lstm_mfma7(
    const float* __restrict__ x, const float* __restrict__ W_ih,
    const float* __restrict__ W_hh, const float* __restrict__ b_ih,
    const float* __restrict__ b_hh, const float* __restrict__ W_fc,
    const float* __restrict__ b_fc, float* __restrict__ out)
{
    const int tid = threadIdx.x;
    const int wave = tid >> 6;
    const int lane = tid & 63;
    const int l15 = lane & 15;
    const int l4 = lane >> 4;
    const int bbase = blockIdx.x * BB;

    __shared__ unsigned short hhi[2][16 * 512];
    __shared__ unsigned short hlo[2][16 * 512];
    __shared__ float dpart[16][BB];
    __shared__ float inp_s[BB];

    for (int i = tid; i < 16 * 512; i += NTHR) { hhi[0][i] = 0; hlo[0][i] = 0; }
    if (tid < BB) inp_s[tid] = x[bbase + tid];

    float biasv[4], wihv[4];
    #pragma unroll
    for (int q = 0; q < 4; ++q) {
        int gg = 256 * q + 16 * wave + l15;
        biasv[q] = b_ih[gg] + b_hh[gg];
        wihv[q] = W_ih[gg];
    }
    const float wfc = W_fc[16 * wave + l15];
    const float bfc = b_fc[0];
    const float* __restrict__ wrow = W_hh + (size_t)(16 * wave + l15) * HID + l4 * 8;
    const int kc_w = wave >> 1;
    const int kwhi = (wave & 1) * 2 + (l15 >> 3);
    const int elemw = l15 & 7;

    float c_r[2][4];
    #pragma unroll
    for (int m = 0; m < 2; ++m)
        #pragma unroll
        for (int r = 0; r < 4; ++r) c_r[m][r] = 0.0f;
    __syncthreads();

    #pragma unroll 1
    for (int t = 0; t < TLEN; ++t) {
        const int p = t & 1;
        f32x4 acc[2][4];
        {
            float dv[2][4];
            #pragma unroll
            for (int m = 0; m < 2; ++m)
                #pragma unroll
                for (int r = 0; r < 4; ++r) dv[m][r] = inp_s[16 * m + 4 * l4 + r];
            #pragma unroll
            for (int m = 0; m < 2; ++m)
                #pragma unroll
                for (int q = 0; q < 4; ++q)
                    #pragma unroll
                    for (int r = 0; r < 4; ++r)
                        acc[m][q][r] = fmaf(dv[m][r], wihv[q], biasv[q]);
        }
        #pragma unroll
        for (int kc = 0; kc < 8; ++kc) {
            short8 ahi[2], alo[2];
            #pragma unroll
            for (int m = 0; m < 2; ++m) {
                int aoff = (m * 8 + kc) * 512 + lane * 8;
                ahi[m] = *(const short8*)&hhi[p][aoff];
                alo[m] = *(const short8*)&hlo[p][aoff];
            }
            #pragma unroll
            for (int q = 0; q < 4; ++q) {
                const float* src = wrow + (size_t)q * 256 * HID + kc * 32;
                float4 wa = *(const float4*)src;
                float4 wb = *(const float4*)(src + 4);
                float ff[8] = {wa.x, wa.y, wa.z, wa.w, wb.x, wb.y, wb.z, wb.w};
                short8 bhi, blo;
                #pragma unroll
                for (int e = 0; e < 8; ++e) {
                    unsigned int u = __float_as_uint(ff[e]);
                    bhi[e] = (short)(u >> 16);
                    float res = ff[e] - __uint_as_float(u & 0xffff0000u);
                    blo[e] = (short)(__float_as_uint(res) >> 16);
                }
                #pragma unroll
                for (int m = 0; m < 2; ++m) {
                    acc[m][q] = __builtin_amdgcn_mfma_f32_16x16x32_bf16(ahi[m], bhi, acc[m][q], 0, 0, 0);
                    acc[m][q] = __builtin_amdgcn_mfma_f32_16x16x32_bf16(alo[m], bhi, acc[m][q], 0, 0, 0);
                    acc[m][q] = __builtin_amdgcn_mfma_f32_16x16x32_bf16(ahi[m], blo, acc[m][q], 0, 0, 0);
                }
            }
        }
        #pragma unroll
        for (int m = 0; m < 2; ++m) {
            #pragma unroll
            for (int r = 0; r < 4; ++r) {
                float gi = acc[m][0][r];
                float gf = acc[m][1][r];
                float gg = acc[m][2][r];
                float go = acc[m][3][r];
                float c = fmaf(sigf(gf), c_r[m][r], sigf(gi) * tanhf_fast(gg));
                c_r[m][r] = c;
                float h = sigf(go) * tanhf_fast(c);
                unsigned short hh = f2bf_rne(h);
                float hres = h - __uint_as_float(__float_as_uint(h) & 0xffff0000u);
                int haddr = (m * 8 + kc_w) * 512 + ((4 * l4 + r) + 16 * kwhi) * 8 + elemw;
                hhi[p ^ 1][haddr] = hh;
                hlo[p ^ 1][haddr] = f2bf_rne(hres);
                float s = h * wfc;
                s += __shfl_xor(s, 1);
                s += __shfl_xor(s, 2);
                s += __shfl_xor(s, 4);
                s += __shfl_xor(s, 8);
                if (l15 == 0) dpart[wave][16 * m + 4 * l4 + r] = s;
            }
        }
        __syncthreads();
        if (tid < BB) {
            float s = bfc;
            #pragma unroll
            for (int w = 0; w < 16; ++w) s += dpart[w][tid];
            inp_s[tid] = s;
            out[(size_t)(bbase + tid) * TLEN + t] = s;
        }
        __syncthreads();
    }
}

extern "C" void kernel_launch(void* const* d_in, const int* in_sizes, int n_in,
                              void* d_out, int out_size, void* d_ws, size_t ws_size,
                              hipStream_t stream) {
    const float* x    = (const float*)d_in[0];
    const float* W_ih = (const float*)d_in[1];
    const float* W_hh = (const float*)d_in[2];
    const float* b_ih = (const float*)d_in[3];
    const float* b_hh = (const float*)d_in[4];
    const float* W_fc = (const float*)d_in[5];
    const float* b_fc = (const float*)d_in[6];
    float* out = (float*)d_out;

    const int BATCH = in_sizes[0];   // 8192

    if (ws_size >= WS_NEEDED) {
        unsigned int* flags = (unsigned int*)((char*)d_ws + FLAGS_OFF);
        unsigned int* xcnt  = (unsigned int*)((char*)d_ws + CNT_OFF);
        init_flags<<<1, 256, 0, stream>>>(flags, xcnt);
        lstm_coop11<<<BATCH / BBG * GSIZE, NTHR, 0, stream>>>(
            x, W_ih, W_hh, b_ih, b_hh, W_fc, b_fc,
            (unsigned short*)d_ws, flags, xcnt, out);
    } else {
        lstm_mfma7<<<BATCH / BB, NTHR, 0, stream>>>(
            x, W_ih, W_hh, b_ih, b_hh, W_fc, b_fc, out);
    }
}